// Round 2
// baseline (314.249 us; speedup 1.0000x reference)
//
#include <hip/hip_runtime.h>
#include <hip/hip_bf16.h>
#include <cstdint>
#include <cstddef>

typedef unsigned short u16;
typedef __attribute__((ext_vector_type(8))) short bf16x8;
typedef __attribute__((ext_vector_type(4))) short bf16x4;
typedef __attribute__((ext_vector_type(4))) float f32x4;

#define AS1 __attribute__((address_space(1)))
#define AS3 __attribute__((address_space(3)))

// round-to-nearest-even f32 -> bf16 bits
static __device__ __forceinline__ u16 f2bf(float f) {
  union { float f; unsigned u; } c;
  c.f = f;
  unsigned r = c.u + 0x7fffu + ((c.u >> 16) & 1u);
  return (u16)(r >> 16);
}

// ---------------- prep kernels ----------------

__global__ __launch_bounds__(256) void cast_x_kernel(const float* __restrict__ in,
                                                     u16* __restrict__ out, int n4) {
  int i = blockIdx.x * blockDim.x + threadIdx.x;
  if (i < n4) {
    float4 v = reinterpret_cast<const float4*>(in)[i];
    ushort4 o;
    o.x = f2bf(v.x); o.y = f2bf(v.y); o.z = f2bf(v.z); o.w = f2bf(v.w);
    reinterpret_cast<ushort4*>(out)[i] = o;
  }
}

// out[C][R] (bf16) = transpose of in[R][C] (f32)
__global__ __launch_bounds__(256) void transpose_cast_kernel(const float* __restrict__ in,
                                                             u16* __restrict__ out,
                                                             int R, int C) {
  __shared__ float tile[32][33];
  int bx = blockIdx.x, by = blockIdx.y;
  int tx = threadIdx.x, ty = threadIdx.y;
  #pragma unroll
  for (int i = ty; i < 32; i += 8)
    tile[i][tx] = in[(size_t)(by * 32 + i) * C + bx * 32 + tx];
  __syncthreads();
  #pragma unroll
  for (int i = ty; i < 32; i += 8)
    out[(size_t)(bx * 32 + i) * R + by * 32 + tx] = f2bf(tile[tx][i]);
}

// ---------------- GEMM mainloop (m97 structure: 128x128 tile, BK=64) ----------------
// A: [M][K] bf16 row-major, Bt: [N][K] bf16 row-major (i.e. B transposed)
// 256 threads = 4 waves in 2x2; each wave computes 64x64 = 4x4 frags of 16x16.
static __device__ __forceinline__ void gemm_mainloop(
    const u16* __restrict__ A, const u16* __restrict__ Bt, int K,
    int brow, int bcol, u16* lsA, u16* lsB, f32x4 acc[4][4]) {
  const int tid  = threadIdx.x;
  const int lane = tid & 63;
  const int wave = tid >> 6;
  const int wr = wave >> 1, wc = wave & 1;
  const int r = lane & 15, g = lane >> 4;

  for (int k0 = 0; k0 < K; k0 += 64) {
    // stage A,B tiles (128x64 bf16 each, LDS linear row-major) via global_load_lds x16B
    #pragma unroll
    for (int i = 0; i < 4; ++i) {
      int chunk = i * 4 + wave;          // 16 chunks x 1KB per tile
      int e = (chunk * 64 + lane) * 8;   // element index in tile
      int rr = e >> 6, cc = e & 63;
      __builtin_amdgcn_global_load_lds(
          (const AS1 void*)(A + (size_t)(brow + rr) * K + k0 + cc),
          (AS3 void*)(lsA + chunk * 512), 16, 0, 0);
      __builtin_amdgcn_global_load_lds(
          (const AS1 void*)(Bt + (size_t)(bcol + rr) * K + k0 + cc),
          (AS3 void*)(lsB + chunk * 512), 16, 0, 0);
    }
    __syncthreads();
    #pragma unroll
    for (int kk = 0; kk < 64; kk += 32) {
      bf16x8 af[4], bfr[4];
      #pragma unroll
      for (int m = 0; m < 4; ++m)
        af[m] = *reinterpret_cast<const bf16x8*>(lsA + (wr * 64 + m * 16 + r) * 64 + kk + g * 8);
      #pragma unroll
      for (int n = 0; n < 4; ++n)
        bfr[n] = *reinterpret_cast<const bf16x8*>(lsB + (wc * 64 + n * 16 + r) * 64 + kk + g * 8);
      #pragma unroll
      for (int m = 0; m < 4; ++m)
        #pragma unroll
        for (int n = 0; n < 4; ++n)
          acc[m][n] = __builtin_amdgcn_mfma_f32_16x16x32_bf16(af[m], bfr[n], acc[m][n], 0, 0, 0);
    }
    __syncthreads();
  }
}

// QKV projection: C[4096][3072] = X @ Wqkv + b; scatter into Q/K/V [B*H][T][64] bf16.
// Q gets the 1/sqrt(64) fold.
__global__ __launch_bounds__(256) void gemm_qkv_kernel(
    const u16* __restrict__ A, const u16* __restrict__ Bt,
    const float* __restrict__ bias,
    u16* __restrict__ Qo, u16* __restrict__ Ko, u16* __restrict__ Vo) {
  __shared__ u16 lsA[128 * 64];
  __shared__ u16 lsB[128 * 64];
  f32x4 acc[4][4];
  #pragma unroll
  for (int m = 0; m < 4; ++m)
    #pragma unroll
    for (int n = 0; n < 4; ++n)
      acc[m][n] = (f32x4){0.f, 0.f, 0.f, 0.f};

  const int brow = blockIdx.y * 128;
  const int bcol = blockIdx.x * 128;
  gemm_mainloop(A, Bt, 1024, brow, bcol, lsA, lsB, acc);

  const int lane = threadIdx.x & 63;
  const int wave = threadIdx.x >> 6;
  const int wr = wave >> 1, wc = wave & 1;
  const int r = lane & 15, g = lane >> 4;
  #pragma unroll
  for (int n = 0; n < 4; ++n) {
    int col = bcol + wc * 64 + n * 16 + r;         // in [0,3072)
    int s = col >> 10, h = (col >> 6) & 15, d = col & 63;
    float bv = bias[col];
    u16* dst = (s == 0) ? Qo : (s == 1) ? Ko : Vo;
    float sc = (s == 0) ? 0.125f : 1.f;            // fold 1/sqrt(D) into Q
    #pragma unroll
    for (int m = 0; m < 4; ++m) {
      #pragma unroll
      for (int j = 0; j < 4; ++j) {
        int rowj = brow + wr * 64 + m * 16 + g * 4 + j;   // b*2048 + t
        int b = rowj >> 11, t = rowj & 2047;
        dst[((size_t)(b * 16 + h) * 2048 + t) * 64 + d] = f2bf((acc[m][n][j] + bv) * sc);
      }
    }
  }
}

// Output projection: out[4096][1024] f32 = attn @ Wout + b_out
__global__ __launch_bounds__(256) void gemm_out_kernel(
    const u16* __restrict__ A, const u16* __restrict__ Bt,
    const float* __restrict__ bias, float* __restrict__ out) {
  __shared__ u16 lsA[128 * 64];
  __shared__ u16 lsB[128 * 64];
  f32x4 acc[4][4];
  #pragma unroll
  for (int m = 0; m < 4; ++m)
    #pragma unroll
    for (int n = 0; n < 4; ++n)
      acc[m][n] = (f32x4){0.f, 0.f, 0.f, 0.f};

  const int brow = blockIdx.y * 128;
  const int bcol = blockIdx.x * 128;
  gemm_mainloop(A, Bt, 1024, brow, bcol, lsA, lsB, acc);

  const int lane = threadIdx.x & 63;
  const int wave = threadIdx.x >> 6;
  const int wr = wave >> 1, wc = wave & 1;
  const int r = lane & 15, g = lane >> 4;
  #pragma unroll
  for (int n = 0; n < 4; ++n) {
    int col = bcol + wc * 64 + n * 16 + r;
    float bv = bias[col];
    #pragma unroll
    for (int m = 0; m < 4; ++m) {
      #pragma unroll
      for (int j = 0; j < 4; ++j) {
        int rowj = brow + wr * 64 + m * 16 + g * 4 + j;
        out[(size_t)rowj * 1024 + col] = acc[m][n][j] + bv;
      }
    }
  }
}

// ---------------- flash attention ----------------
// 1 wave per (bh, 16 q-rows). Swapped QK^T: S^T = mfma(K_frag, Q_frag) so the
// S^T register layout IS the A-fragment of the PV 16x16x16 mfma (no transpose).
// grid: (T/16, B*H), block: 64
__global__ __launch_bounds__(64) void attn_kernel(
    const u16* __restrict__ Q, const u16* __restrict__ K,
    const u16* __restrict__ V, u16* __restrict__ O) {
  __shared__ u16 vtile[16 * 64];
  const int lane = threadIdx.x;
  const int r = lane & 15, g = lane >> 4;
  const int qt = blockIdx.x;
  const int bh = blockIdx.y;
  const int q0 = qt * 16;
  const size_t base = (size_t)bh * 2048 * 64;

  // Q fragments (B-operand of swapped mfma): lane holds Q[q=r][kd = g*8..g*8+7 (+32)]
  bf16x8 qf0 = *reinterpret_cast<const bf16x8*>(Q + base + (size_t)(q0 + r) * 64 + g * 8);
  bf16x8 qf1 = *reinterpret_cast<const bf16x8*>(Q + base + (size_t)(q0 + r) * 64 + 32 + g * 8);

  f32x4 o[4];
  #pragma unroll
  for (int n = 0; n < 4; ++n) o[n] = (f32x4){0.f, 0.f, 0.f, 0.f};
  float m = -INFINITY, lsum = 0.f;

  for (int kt = 0; kt <= qt; ++kt) {
    const u16* Kt = K + base + (size_t)kt * 16 * 64;
    const u16* Vt = V + base + (size_t)kt * 16 * 64;
    // stage V tile (16x64 bf16 = 2KB) to LDS, linear
    #pragma unroll
    for (int i = 0; i < 2; ++i)
      __builtin_amdgcn_global_load_lds((const AS1 void*)(Vt + (i * 64 + lane) * 8),
                                       (AS3 void*)(vtile + i * 512), 16, 0, 0);
    // K fragments direct from global (L2-resident)
    bf16x8 kf0 = *reinterpret_cast<const bf16x8*>(Kt + r * 64 + g * 8);
    bf16x8 kf1 = *reinterpret_cast<const bf16x8*>(Kt + r * 64 + 32 + g * 8);

    f32x4 st = (f32x4){0.f, 0.f, 0.f, 0.f};
    st = __builtin_amdgcn_mfma_f32_16x16x32_bf16(kf0, qf0, st, 0, 0, 0);
    st = __builtin_amdgcn_mfma_f32_16x16x32_bf16(kf1, qf1, st, 0, 0, 0);
    // st[j] = S^T[key = kt*16 + g*4 + j][q = q0 + r]  (already scaled via Q)

    const int qg = q0 + r;
    float s[4];
    #pragma unroll
    for (int j = 0; j < 4; ++j) {
      int key = kt * 16 + g * 4 + j;
      s[j] = (key <= qg) ? st[j] : -INFINITY;
    }
    float pmax = fmaxf(fmaxf(s[0], s[1]), fmaxf(s[2], s[3]));
    pmax = fmaxf(pmax, __shfl_xor(pmax, 16));
    pmax = fmaxf(pmax, __shfl_xor(pmax, 32));
    float m_new = fmaxf(m, pmax);
    float scale = __expf(m - m_new);

    float p[4];
    #pragma unroll
    for (int j = 0; j < 4; ++j) p[j] = __expf(s[j] - m_new);
    float rowsum = p[0] + p[1] + p[2] + p[3];
    rowsum += __shfl_xor(rowsum, 16);
    rowsum += __shfl_xor(rowsum, 32);
    lsum = lsum * scale + rowsum;
    m = m_new;

    bf16x4 pf;
    #pragma unroll
    for (int j = 0; j < 4; ++j) pf[j] = (short)f2bf(p[j]);

    // O-accumulator rows are q' = g*4+j — fetch their rescale factor
    float osc[4];
    #pragma unroll
    for (int j = 0; j < 4; ++j) osc[j] = __shfl(scale, (lane & 48) | (g * 4 + j));
    #pragma unroll
    for (int n = 0; n < 4; ++n)
      #pragma unroll
      for (int j = 0; j < 4; ++j) o[n][j] *= osc[j];

    __syncthreads();  // drain vmcnt: V tile ready
    #pragma unroll
    for (int n = 0; n < 4; ++n) {
      bf16x4 vf;
      #pragma unroll
      for (int j = 0; j < 4; ++j)
        vf[j] = (short)vtile[(g * 4 + j) * 64 + n * 16 + r];
      o[n] = __builtin_amdgcn_mfma_f32_16x16x16bf16_1k(pf, vf, o[n], 0, 0, 0);
    }
    __syncthreads();  // LDS reads done before next tile's DMA overwrites
  }

  // epilogue: normalize and write attn_out [B][T][H*64+d]
  const int b = bh >> 4, h = bh & 15;
  float linv[4];
  #pragma unroll
  for (int j = 0; j < 4; ++j)
    linv[j] = 1.f / __shfl(lsum, (lane & 48) | (g * 4 + j));
  #pragma unroll
  for (int n = 0; n < 4; ++n) {
    #pragma unroll
    for (int j = 0; j < 4; ++j) {
      size_t row = (size_t)b * 2048 + q0 + g * 4 + j;
      O[row * 1024 + h * 64 + n * 16 + r] = f2bf(o[n][j] * linv[j]);
    }
  }
}

// ---------------- launch ----------------

extern "C" void kernel_launch(void* const* d_in, const int* in_sizes, int n_in,
                              void* d_out, int out_size, void* d_ws, size_t ws_size,
                              hipStream_t stream) {
  const float* x    = (const float*)d_in[0];
  const float* Wqkv = (const float*)d_in[1];
  const float* bqkv = (const float*)d_in[2];
  const float* Wout = (const float*)d_in[3];
  const float* bout = (const float*)d_in[4];
  float* out = (float*)d_out;

  char* p = (char*)d_ws;
  u16* xbf   = (u16*)p; p += (size_t)4096 * 1024 * 2;
  u16* wqkvT = (u16*)p; p += (size_t)3072 * 1024 * 2;
  u16* woutT = (u16*)p; p += (size_t)1024 * 1024 * 2;
  u16* Qb    = (u16*)p; p += (size_t)32 * 2048 * 64 * 2;
  u16* Kb    = (u16*)p; p += (size_t)32 * 2048 * 64 * 2;
  u16* Vb    = (u16*)p; p += (size_t)32 * 2048 * 64 * 2;
  u16* attn  = (u16*)p; p += (size_t)4096 * 1024 * 2;

  cast_x_kernel<<<4096, 256, 0, stream>>>(x, xbf, 4096 * 1024 / 4);
  transpose_cast_kernel<<<dim3(96, 32), dim3(32, 8), 0, stream>>>(Wqkv, wqkvT, 1024, 3072);
  transpose_cast_kernel<<<dim3(32, 32), dim3(32, 8), 0, stream>>>(Wout, woutT, 1024, 1024);
  gemm_qkv_kernel<<<dim3(24, 32), 256, 0, stream>>>(xbf, wqkvT, bqkv, Qb, Kb, Vb);
  attn_kernel<<<dim3(128, 32), 64, 0, stream>>>(Qb, Kb, Vb, attn);
  gemm_out_kernel<<<dim3(8, 32), 256, 0, stream>>>(attn, woutT, bout, out);
}